// Round 6
// baseline (346.099 us; speedup 1.0000x reference)
//
#include <hip/hip_runtime.h>
#include <hip/hip_bf16.h>
#include <math.h>

// Attention block: y = out_proj(causal_softmax(rope(q)·rope(k)^T)·v)
// B=2 T=2048 C=2048 Hq=32 Hkv=8 D=64. bf16 MFMA 16x16x32, fp32 accumulate.
// R6: (a) attn is LDS-pipe-bound (240 LDS-cyc/wave-tile vs 78 MFMA-cyc) ->
// each wave now computes TWO 16-row q-fragments (128 q-rows/block) against
// the same K/V LDS reads: 288 LDS-cyc per wave-tile for 2x the FLOP.
// Blocks pair (Q, 15-Q): 66 frag-tiles each, perfectly balanced; frag0
// skips its fully-masked last tile. (b) gemm_qkv stages A (=x) directly
// from fp32 with in-register convert (loads issued before the B-DMAs so
// the pack's vmcnt wait leaves the DMAs in flight); cvt_all is weights-only.

typedef __attribute__((ext_vector_type(8))) short short8;
typedef __attribute__((ext_vector_type(4))) float f32x4;

#define MFMA16(a,b,c) __builtin_amdgcn_mfma_f32_16x16x32_bf16((a),(b),(c),0,0,0)
#define QSCALE 0.18033688011112043f   // (1/sqrt(64))*log2(e): exp2-domain softmax
#define NFREQ  (-13.28771237954945f / 32.0f)  // -log2(10000)/32

__device__ __forceinline__ ushort f2bf(float f) {
  union { float f; unsigned u; } x; x.f = f;
  unsigned r = x.u + 0x7fffu + ((x.u >> 16) & 1u);   // RNE
  return (ushort)(r >> 16);
}
// round-half-up packed bf16 pair (5 int ops)
__device__ __forceinline__ uint pkbf(float a, float b) {
  union { float f; unsigned u; } x, y; x.f = a; y.f = b;
  return ((x.u + 0x8000u) >> 16) | ((y.u + 0x8000u) & 0xffff0000u);
}

__device__ __forceinline__ void g2l16(const void* g, void* l) {
  __builtin_amdgcn_global_load_lds(
      (__attribute__((address_space(1))) void*)g,
      (__attribute__((address_space(3))) void*)l, 16, 0, 0);
}

// fp32->bf16 for the four weight matrices only (x converts inline in gemm_qkv)
__global__ void cvt_all(const float* __restrict__ wq, const float* __restrict__ wk,
                        const float* __restrict__ wv, const float* __restrict__ wo,
                        ushort* __restrict__ wqkv, ushort* __restrict__ wo_bf) {
  int i = blockIdx.x * 256 + threadIdx.x;
  const float4* src; ushort* dst; int off;
  if (i < 1048576)      { src = (const float4*)wq; dst = wqkv;             off = i; }
  else if (i < 1310720) { src = (const float4*)wk; dst = wqkv + 4194304;   off = i - 1048576; }
  else if (i < 1572864) { src = (const float4*)wv; dst = wqkv + 5242880;   off = i - 1310720; }
  else                  { src = (const float4*)wo; dst = wo_bf;            off = i - 1572864; }
  float4 v = src[off];
  ushort4 o;
  o.x = f2bf(v.x); o.y = f2bf(v.y); o.z = f2bf(v.z); o.w = f2bf(v.w);
  ((ushort4*)dst)[off] = o;
}

// QKV GEMM with fused RoPE/scatter epilogue and inline fp32 A conversion.
// M=4096, N=3072, K=2048, grid (24,32). x<16 -> q(rope->qr), 16..19 ->
// k(rope->kr), 20..23 -> v(transpose->vt).
__global__ __launch_bounds__(256, 3)
void gemm_qkv(const float* __restrict__ X, const ushort* __restrict__ Bw,
              const float* __restrict__ bq, const float* __restrict__ bk,
              const float* __restrict__ bv,
              ushort* __restrict__ qr, ushort* __restrict__ kr,
              ushort* __restrict__ vt) {
  const int K = 2048;
  __shared__ ushort As[2][128*32];
  __shared__ ushort Bs[2][128*32];
  const int tid = threadIdx.x;
  const int wave = tid >> 6, lane = tid & 63;
  const int wm = wave >> 1, wn = wave & 1;
  const int quad = lane >> 4, l16 = lane & 15;
  const int swg = (l16 >> 1) & 3;
  const int m0 = blockIdx.y * 128, n0 = blockIdx.x * 128;

  // A staging via registers: thread owns row=tid>>1, chunks (tid&1)*2+{0,1}
  const int arow = tid >> 1, acb = (tid & 1) * 2;
  const float* aptr = X + (size_t)(m0 + arow) * K + acb * 8;
  const int acl0 = (acb     ) ^ ((arow >> 1) & 3);
  const int acl1 = (acb + 1) ^ ((arow >> 1) & 3);

  f32x4 acc[4][4] = {};
  float4 va0, va1, va2, va3;

  auto loadA = [&](int k0) {
    const float4* p = (const float4*)(aptr + k0);
    va0 = p[0]; va1 = p[1]; va2 = p[2]; va3 = p[3];
  };
  auto writeA = [&](int buf) {
    uint4 w0, w1;
    w0.x = pkbf(va0.x, va0.y); w0.y = pkbf(va0.z, va0.w);
    w0.z = pkbf(va1.x, va1.y); w0.w = pkbf(va1.z, va1.w);
    w1.x = pkbf(va2.x, va2.y); w1.y = pkbf(va2.z, va2.w);
    w1.z = pkbf(va3.x, va3.y); w1.w = pkbf(va3.z, va3.w);
    *(uint4*)(As[buf] + arow*32 + acl0*8) = w0;
    *(uint4*)(As[buf] + arow*32 + acl1*8) = w1;
  };
  auto stageB = [&](int buf, int k0) {
#pragma unroll
    for (int i = 0; i < 2; ++i) {
      int cbase = (i*4 + wave) * 64;
      int p = cbase + lane;
      int row = p >> 2, pcb = p & 3;
      int cl = pcb ^ ((row >> 1) & 3);
      g2l16(Bw + (size_t)(n0 + row) * K + k0 + cl * 8, Bs[buf] + (size_t)cbase * 8);
    }
  };

  loadA(0); stageB(0, 0); writeA(0);
  for (int k0 = 0; k0 < K; k0 += 32) {
    __syncthreads();
    int cur = (k0 >> 5) & 1;
    bool more = (k0 + 32) < K;
    if (more) { loadA(k0 + 32); stageB(cur ^ 1, k0 + 32); }

    short8 af[4], bfr[4];
#pragma unroll
    for (int mi = 0; mi < 4; ++mi)
      af[mi] = *(const short8*)(As[cur] + (wm*64 + mi*16 + l16)*32 + ((quad ^ swg) * 8));
#pragma unroll
    for (int ni = 0; ni < 4; ++ni)
      bfr[ni] = *(const short8*)(Bs[cur] + (wn*64 + ni*16 + l16)*32 + ((quad ^ swg) * 8));
#pragma unroll
    for (int mi = 0; mi < 4; ++mi)
#pragma unroll
      for (int ni = 0; ni < 4; ++ni)
        acc[mi][ni] = MFMA16(af[mi], bfr[ni], acc[mi][ni]);

    if (more) writeA(cur ^ 1);   // vmcnt waits only the A loads (older than DMAs)
  }

  // ---- fused epilogue ----
  const int bb = m0 >> 11;                 // batch
  const int tb = (m0 & 2047) + wm*64;      // token base for this wave

  if (blockIdx.x < 20) {
    const bool isq = blockIdx.x < 16;
    const float scale = isq ? QSCALE : 1.0f;
#pragma unroll
    for (int ni = 0; ni < 2; ++ni) {
      int n = n0 + wn*64 + ni*16 + l16;
      int d = ni*16 + l16;                 // < 32
      float bias1, bias2;
      ushort* dst;
      if (isq) {
        bias1 = bq[n]; bias2 = bq[n + 32];
        dst = qr + ((size_t)(bb*32 + (n >> 6)) * 2048) * 64 + d;
      } else {
        bias1 = bk[n - 2048]; bias2 = bk[n - 2016];
        dst = kr + ((size_t)(bb*8 + ((n >> 6) - 32)) * 2048) * 64 + d;
      }
      float invf = exp2f((float)d * NFREQ);
#pragma unroll
      for (int mi = 0; mi < 4; ++mi) {
#pragma unroll
        for (int r = 0; r < 4; ++r) {
          int t = tb + mi*16 + quad*4 + r;
          float x1 = acc[mi][ni][r]   + bias1;
          float x2 = acc[mi][ni+2][r] + bias2;
          float f = (float)t * invf;
          float sn = __sinf(f), cs = __cosf(f);
          dst[(size_t)t*64]      = f2bf((x1*cs - x2*sn) * scale);
          dst[(size_t)t*64 + 32] = f2bf((x2*cs + x1*sn) * scale);
        }
      }
    }
  } else {
#pragma unroll
    for (int ni = 0; ni < 4; ++ni) {
      int n = n0 + wn*64 + ni*16 + l16;
      int d = ni*16 + l16;
      float bias = bv[n - 2560];
      ushort* dst = vt + ((size_t)(bb*8 + ((n - 2560) >> 6)) * 64 + d) * 2048;
#pragma unroll
      for (int mi = 0; mi < 4; ++mi) {
        int t = tb + mi*16 + quad*4;
        uint2 pk;
        pk.x = (uint)f2bf(acc[mi][ni][0]+bias) | ((uint)f2bf(acc[mi][ni][1]+bias) << 16);
        pk.y = (uint)f2bf(acc[mi][ni][2]+bias) | ((uint)f2bf(acc[mi][ni][3]+bias) << 16);
        *(uint2*)(dst + t) = pk;
      }
    }
  }
}

// 128x128 GEMM (output projection), BK=32, dbuf, fp32 out + bias.
__global__ __launch_bounds__(256, 3)
void gemm128(const ushort* __restrict__ A, const ushort* __restrict__ Bw,
             const float* __restrict__ b0,
             float* __restrict__ Cout, int M, int N, int K) {
  __shared__ ushort As[2][128*32];
  __shared__ ushort Bs[2][128*32];
  const int tid = threadIdx.x;
  const int wave = tid >> 6, lane = tid & 63;
  const int wm = wave >> 1, wn = wave & 1;
  const int quad = lane >> 4, l16 = lane & 15;
  const int swg = (l16 >> 1) & 3;
  const int m0 = blockIdx.y * 128, n0 = blockIdx.x * 128;

  f32x4 acc[4][4] = {};

  auto stage = [&](int buf, int k0) {
#pragma unroll
    for (int i = 0; i < 2; ++i) {
      int cbase = (i*4 + wave) * 64;
      int p = cbase + lane;
      int row = p >> 2, pcb = p & 3;
      int cl = pcb ^ ((row >> 1) & 3);
      g2l16(A  + (size_t)(m0 + row) * K + k0 + cl * 8, As[buf] + (size_t)cbase * 8);
      g2l16(Bw + (size_t)(n0 + row) * K + k0 + cl * 8, Bs[buf] + (size_t)cbase * 8);
    }
  };

  stage(0, 0);
  for (int k0 = 0; k0 < K; k0 += 32) {
    __syncthreads();
    int cur = (k0 >> 5) & 1;
    if (k0 + 32 < K) stage(cur ^ 1, k0 + 32);

    short8 af[4], bfr[4];
#pragma unroll
    for (int mi = 0; mi < 4; ++mi)
      af[mi] = *(const short8*)(As[cur] + (wm*64 + mi*16 + l16)*32 + ((quad ^ swg) * 8));
#pragma unroll
    for (int ni = 0; ni < 4; ++ni)
      bfr[ni] = *(const short8*)(Bs[cur] + (wn*64 + ni*16 + l16)*32 + ((quad ^ swg) * 8));
#pragma unroll
    for (int mi = 0; mi < 4; ++mi)
#pragma unroll
      for (int ni = 0; ni < 4; ++ni)
        acc[mi][ni] = MFMA16(af[mi], bfr[ni], acc[mi][ni]);
  }

#pragma unroll
  for (int ni = 0; ni < 4; ++ni) {
    int n = n0 + wn*64 + ni*16 + l16;
    float bias = b0[n];
#pragma unroll
    for (int mi = 0; mi < 4; ++mi) {
#pragma unroll
      for (int r = 0; r < 4; ++r) {
        int m = m0 + wm*64 + mi*16 + quad*4 + r;
        Cout[(size_t)m * N + n] = acc[mi][ni][r] + bias;
      }
    }
  }
}

// Flash attention (S^T form), causal, GQA, shift-free exp2 softmax.
// Block = 128 q-rows (4 waves x 2 fragments of 16 rows), paired (Q, 15-Q).
// K/V LDS fragment reads are shared by both q-fragments -> LDS-pipe cost
// per FLOP drops 1.67x vs the 64-row version. frag0 skips its fully-masked
// last kt-tile; frag0 masks at kt==2Q, frag1 at kt==2Q+1.
__global__ __launch_bounds__(256, 2)
void attn(const ushort* __restrict__ Qm, const ushort* __restrict__ Kb,
          const ushort* __restrict__ Vt, ushort* __restrict__ Y) {
  __shared__ ushort Ks[2][64*64];
  __shared__ ushort Vs[2][64*64];
  __shared__ ushort Ps[8*16*64];      // [wave][frag] 16x64, xor-swizzled
  const int tid = threadIdx.x, wave = tid >> 6, lane = tid & 63;
  const int quad = lane >> 4, l16 = lane & 15;
  const int h = blockIdx.y, b = blockIdx.z;
  const int hk = h >> 2;
  const ushort* Qb = Qm + ((size_t)(b*32 + h)  * 2048) * 64;
  const ushort* Kg = Kb + ((size_t)(b*8 + hk) * 2048) * 64;
  const ushort* Vg = Vt + ((size_t)(b*8 + hk) * 64) * 2048;
  const int sw = l16 & 7;

  auto stage = [&](int buf, int kt) {
#pragma unroll
    for (int i = 0; i < 2; ++i) {
      int cbase = (i*4 + wave) * 64;
      int p = cbase + lane;
      int row = p >> 3, pcb = p & 7;
      int cl = pcb ^ (row & 7);
      g2l16(Kg + (size_t)(kt*64 + row)*64 + cl*8, Ks[buf] + (size_t)cbase*8);
      g2l16(Vg + (size_t)row*2048 + kt*64 + cl*8, Vs[buf] + (size_t)cbase*8);
    }
  };

  for (int pass = 0; pass < 2; ++pass) {
    const int Q = pass ? (15 - blockIdx.x) : blockIdx.x;
    const int q0 = Q * 128;
    const int nkt = 2*Q + 2;

    short8 qf[2][2];
#pragma unroll
    for (int qi = 0; qi < 2; ++qi) {
      int qrow = q0 + qi*64 + wave*16 + l16;
      qf[qi][0] = *(const short8*)(Qb + (size_t)qrow*64 + quad*8);
      qf[qi][1] = *(const short8*)(Qb + (size_t)qrow*64 + 32 + quad*8);
    }

    f32x4 o0[4] = {}, o1[4] = {};
    f32x4 l40 = {0.f,0.f,0.f,0.f}, l41 = {0.f,0.f,0.f,0.f};

    __syncthreads();            // LDS reuse across passes
    stage(0, 0);

    for (int kt = 0; kt < nkt; ++kt) {
      __syncthreads();          // drain: prefetch was issued one tile ago
      int cur = kt & 1;
      bool f0 = kt <= 2*Q;      // frag0's last tile is kt==2Q
      if (kt + 1 < nkt) stage(cur ^ 1, kt + 1);

      // S^T = K Q^T for both fragments; K frags read once, shared
      f32x4 s0[4], s1[4];
#pragma unroll
      for (int kb = 0; kb < 4; ++kb) {
        const ushort* krow = Ks[cur] + (kb*16 + l16)*64;
        short8 kf0 = *(const short8*)(krow + ((quad       ^ sw) * 8));
        short8 kf1 = *(const short8*)(krow + (((4 + quad) ^ sw) * 8));
        if (f0) {
          f32x4 z = {0.f,0.f,0.f,0.f};
          z = MFMA16(kf0, qf[0][0], z);
          s0[kb] = MFMA16(kf1, qf[0][1], z);
        }
        f32x4 z1 = {0.f,0.f,0.f,0.f};
        z1 = MFMA16(kf0, qf[1][0], z1);
        s1[kb] = MFMA16(kf1, qf[1][1], z1);
      }

      int ql = wave*16 + l16;
      if (kt == 2*Q) {          // frag0 diagonal
#pragma unroll
        for (int kb = 0; kb < 4; ++kb) {
          int keyl = kb*16 + quad*4;
#pragma unroll
          for (int r = 0; r < 4; ++r)
            if (keyl + r > ql) s0[kb][r] = -INFINITY;
        }
      }
      if (kt == 2*Q + 1) {      // frag1 diagonal
#pragma unroll
        for (int kb = 0; kb < 4; ++kb) {
          int keyl = kb*16 + quad*4;
#pragma unroll
          for (int r = 0; r < 4; ++r)
            if (keyl + r > ql) s1[kb][r] = -INFINITY;
        }
      }

      ushort* Pw0 = Ps + (wave*2 + 0) * 1024;
      ushort* Pw1 = Ps + (wave*2 + 1) * 1024;

      if (f0) {
#pragma unroll
        for (int kb = 0; kb < 4; ++kb)
#pragma unroll
          for (int r = 0; r < 4; ++r)
            s0[kb][r] = __builtin_amdgcn_exp2f(s0[kb][r]);
        l40 += (s0[0] + s0[1]) + (s0[2] + s0[3]);
#pragma unroll
        for (int kb = 0; kb < 4; ++kb) {
          uint2 pk;
          pk.x = pkbf(s0[kb][0], s0[kb][1]);
          pk.y = pkbf(s0[kb][2], s0[kb][3]);
          int G = (kb*2 + (quad >> 1)) ^ sw;
          *(uint2*)((char*)Pw0 + l16*128 + G*16 + (quad & 1)*8) = pk;
        }
      }
#pragma unroll
      for (int kb = 0; kb < 4; ++kb)
#pragma unroll
        for (int r = 0; r < 4; ++r)
          s1[kb][r] = __builtin_amdgcn_exp2f(s1[kb][r]);
      l41 += (s1[0] + s1[1]) + (s1[2] + s1[3]);
#pragma unroll
      for (int kb = 0; kb < 4; ++kb) {
        uint2 pk;
        pk.x = pkbf(s1[kb][0], s1[kb][1]);
        pk.y = pkbf(s1[kb][2], s1[kb][3]);
        int G = (kb*2 + (quad >> 1)) ^ sw;
        *(uint2*)((char*)Pw1 + l16*128 + G*16 + (quad & 1)*8) = pk;
      }

      // O^T += V^T P^T; V frags read once, shared by both fragments
#pragma unroll
      for (int kc = 0; kc < 2; ++kc) {
        short8 pf0;
        if (f0) pf0 = *(const short8*)((char*)Pw0 + l16*128 + (((kc*4 + quad) ^ sw) * 16));
        short8 pf1 = *(const short8*)((char*)Pw1 + l16*128 + (((kc*4 + quad) ^ sw) * 16));
#pragma unroll
        for (int db = 0; db < 4; ++db) {
          const ushort* vrow = Vs[cur] + (db*16 + l16)*64;
          short8 vf = *(const short8*)(vrow + (((kc*4 + quad) ^ sw) * 8));
          if (f0) o0[db] = MFMA16(vf, pf0, o0[db]);
          o1[db] = MFMA16(vf, pf1, o1[db]);
        }
      }
    }

    // epilogue per fragment
#pragma unroll
    for (int qi = 0; qi < 2; ++qi) {
      f32x4 l4 = qi ? l41 : l40;
      f32x4* o = qi ? o1 : o0;
      float l = (l4[0] + l4[1]) + (l4[2] + l4[3]);
      l += __shfl_xor(l, 16);
      l += __shfl_xor(l, 32);
      float inv = 1.0f / l;
      int q = q0 + qi*64 + wave*16 + l16;
#pragma unroll
      for (int db = 0; db < 4; ++db) {
        size_t base = ((size_t)(b*2048 + q)) * 2048 + h*64 + db*16 + quad*4;
        ((uint*)Y)[base >> 1]       = pkbf(o[db][0]*inv, o[db][1]*inv);
        ((uint*)Y)[(base >> 1) + 1] = pkbf(o[db][2]*inv, o[db][3]*inv);
      }
    }
  }
}

extern "C" void kernel_launch(void* const* d_in, const int* in_sizes, int n_in,
                              void* d_out, int out_size, void* d_ws, size_t ws_size,
                              hipStream_t stream) {
  (void)in_sizes; (void)n_in; (void)out_size; (void)ws_size;
  const float* x  = (const float*)d_in[0];
  const float* Wq = (const float*)d_in[1];
  const float* bq = (const float*)d_in[2];
  const float* Wk = (const float*)d_in[3];
  const float* bk = (const float*)d_in[4];
  const float* Wv = (const float*)d_in[5];
  const float* bv = (const float*)d_in[6];
  const float* Wo = (const float*)d_in[7];
  const float* bo = (const float*)d_in[8];
  float* out = (float*)d_out;

  ushort* ws    = (ushort*)d_ws;
  ushort* wqkv  = ws;                        // 6291456  [3072][2048]
  ushort* wo_bf = wqkv + 6291456;            // 4194304
  ushort* qr    = wo_bf + 4194304;           // 8388608  [2][32][2048][64]
  ushort* kr    = qr + 8388608;              // 2097152  [2][8][2048][64]
  ushort* vt    = kr + 2097152;              // 2097152  [2][8][64][2048]
  ushort* Y     = vt + 2097152;              // 8388608  [4096][2048]

  cvt_all<<<10240, 256, 0, stream>>>(Wq, Wk, Wv, Wo, wqkv, wo_bf);
  gemm_qkv<<<dim3(24, 32), 256, 0, stream>>>(x, wqkv, bq, bk, bv, qr, kr, vt);
  attn<<<dim3(8, 32, 2), 256, 0, stream>>>(qr, kr, vt, Y);
  gemm128<<<dim3(16, 32), 256, 0, stream>>>(Y, wo_bf, bo, out, 4096, 2048, 2048);
}